// Round 4
// baseline (1928.487 us; speedup 1.0000x reference)
//
#include <hip/hip_runtime.h>
#include <stdint.h>

typedef unsigned short u16;

#define DH 128   // D = H*C
#define NH 4     // heads
#define CH 32    // channels per head

__device__ __forceinline__ float bf2f(u16 u) {
    union { unsigned int i; float f; } c; c.i = ((unsigned int)u) << 16; return c.f;
}
__device__ __forceinline__ u16 f2bf(float f) {
    union { float f; unsigned int i; } c; c.f = f;
    unsigned int x = c.i;
    x += 0x7FFFu + ((x >> 16) & 1u);   // round-to-nearest-even
    return (u16)(x >> 16);
}
__device__ __forceinline__ float lrelu(float v) { return v > 0.f ? v : 0.2f * v; }

// ---- naive GEMM (f32): h_in (+lin_b) -> d_out f32 ; xp -> ws bf16 --------
__global__ __launch_bounds__(256) void gemm_naive(
        const float* __restrict__ x, const float* __restrict__ lin_w,
        const float* __restrict__ lin_b, const float* __restrict__ gat_w,
        float* __restrict__ h_out, u16* __restrict__ xp, int N) {
    int t = blockIdx.x * 256 + threadIdx.x;      // t = row*256 + col
    int row = t >> 8;
    int col = t & 255;
    if (row >= N) return;
    const float* xr = x + (size_t)row * DH;
    float acc = 0.f;
    if (col < DH) {
        const float* wc = lin_w + col;
        for (int k = 0; k < DH; k++)
            acc += xr[k] * wc[k * DH];
        h_out[(size_t)row * DH + col] = acc + lin_b[col];
    } else {
        int c2 = col - DH;
        const float* wc = gat_w + c2;
        for (int k = 0; k < DH; k++)
            acc += xr[k] * wc[k * DH];
        xp[(size_t)row * DH + c2] = f2bf(acc);
    }
}

// ---- per-(node,head) attention logits ------------------------------------
__global__ __launch_bounds__(256) void att_kernel(
        const u16* __restrict__ xp, const float* __restrict__ att_src,
        const float* __restrict__ att_dst, float* __restrict__ a_src,
        float* __restrict__ a_dst, int N) {
    int t = blockIdx.x * blockDim.x + threadIdx.x;   // t = n*4 + h
    if (t >= N * NH) return;
    int h = t & 3;
    const u16* v   = xp + (size_t)t * CH;
    const float* ws = att_src + h * CH;
    const float* wd = att_dst + h * CH;
    float s = 0.f, d = 0.f;
    for (int c = 0; c < CH; c++) {
        float xv = bf2f(v[c]);
        s += xv * ws[c];
        d += xv * wd[c];
    }
    a_src[t] = s;
    a_dst[t] = d;
}

// ---- denom[d][h] += exp(e)  (no max subtraction: |e| <~ 3, exp safe) ----
__global__ __launch_bounds__(256) void ek_sum(
        const int* __restrict__ ei, int E, int N,
        const float* __restrict__ a_src, const float* __restrict__ a_dst,
        float* __restrict__ denom) {
    int i = blockIdx.x * blockDim.x + threadIdx.x;
    if (i >= E + N) return;
    int s, d;
    if (i < E) { s = ei[i]; d = ei[E + i]; } else { s = i - E; d = s; }
    s = min(max(s, 0), N - 1);
    d = min(max(d, 0), N - 1);
    for (int h = 0; h < NH; h++) {
        float e = lrelu(a_src[s * NH + h] + a_dst[d * NH + h]);
        atomicAdd(&denom[d * NH + h], expf(e));
    }
}

// ---- agg[d][c] += alpha * xp[s][c] for c in this pass's chunk -----------
__global__ __launch_bounds__(256) void ek_agg(
        const int* __restrict__ ei, int E, int N,
        const float* __restrict__ a_src, const float* __restrict__ a_dst,
        const float* __restrict__ denom, const u16* __restrict__ xp,
        float* __restrict__ agg, int pass, int CB) {
    long long t = (long long)blockIdx.x * blockDim.x + threadIdx.x;
    int i = (int)(t >> 5);
    int l = (int)(t & 31);
    if (i >= E + N) return;
    int s, d;
    if (i < E) { s = ei[i]; d = ei[E + i]; } else { s = i - E; d = s; }
    s = min(max(s, 0), N - 1);
    d = min(max(d, 0), N - 1);
    float al[NH];
    for (int h = 0; h < NH; h++) {
        float e = lrelu(a_src[s * NH + h] + a_dst[d * NH + h]);
        al[h] = expf(e) / denom[d * NH + h];
    }
    const u16* xr = xp + (size_t)s * DH;
    float* ar = agg + (size_t)d * CB;
    for (int c = l; c < CB; c += 32) {
        int gcol = pass * CB + c;
        atomicAdd(ar + c, al[gcol >> 5] * bf2f(xr[gcol]));
    }
}

// ---- BN column stats for one pass chunk ---------------------------------
__global__ __launch_bounds__(256) void stats_kernel(
        const float* __restrict__ agg, int N, int CB, int lgCB, int pass,
        float* __restrict__ colsum, float* __restrict__ colsumsq) {
    int c_local = threadIdx.x & (CB - 1);
    int sub     = threadIdx.x >> lgCB;
    int stride  = 256 >> lgCB;
    int rpb = (N + gridDim.x - 1) / gridDim.x;
    int r0  = blockIdx.x * rpb;
    int r1  = min(N, r0 + rpb);
    float s1 = 0.f, s2 = 0.f;
    for (int r = r0 + sub; r < r1; r += stride) {
        float v = agg[(size_t)r * CB + c_local];
        s1 += v; s2 += v * v;
    }
    atomicAdd(&colsum[pass * CB + c_local], s1);
    atomicAdd(&colsumsq[pass * CB + c_local], s2);
}

// ---- BN normalize + ELU + residual; sanitize non-finite to sentinel -----
// gat_bias cancels exactly in training-mode BN (shifts column mean only)
__global__ __launch_bounds__(256) void final_kernel(
        const float* __restrict__ agg, const float* __restrict__ colsum,
        const float* __restrict__ colsumsq, const float* __restrict__ gamma,
        const float* __restrict__ beta, float* __restrict__ out, int N,
        int CB, int lgCB, int pass) {
    int idx = blockIdx.x * blockDim.x + threadIdx.x;
    if (idx >= N * CB) return;
    int c_local = idx & (CB - 1);
    int row     = idx >> lgCB;
    int gcol    = pass * CB + c_local;
    float inv_n = 1.0f / (float)N;
    float mu  = colsum[gcol] * inv_n;
    float var = colsumsq[gcol] * inv_n - mu * mu;
    float rstd = rsqrtf(var + 1e-5f);
    float v = (agg[idx] - mu) * rstd * gamma[gcol] + beta[gcol];
    v = v > 0.f ? v : (expf(v) - 1.f);            // ELU(alpha=1)
    size_t o = (size_t)row * DH + gcol;
    float r = out[o] + v;                         // + h_in (already in d_out)
    // tripwire: non-finite -> 512 sentinel (diagnostic, no-op when correct)
    if (!(r >= -1e30f && r <= 1e30f)) r = 512.0f;
    out[o] = r;
}

extern "C" void kernel_launch(void* const* d_in, const int* in_sizes, int n_in,
                              void* d_out, int out_size, void* d_ws, size_t ws_size,
                              hipStream_t stream) {
    const float* x        = (const float*)d_in[0];
    const int*   ei       = (const int*)d_in[1];
    const float* lin_w    = (const float*)d_in[2];
    const float* lin_b    = (const float*)d_in[3];
    const float* gat_w    = (const float*)d_in[4];
    const float* att_src  = (const float*)d_in[5];
    const float* att_dst  = (const float*)d_in[6];
    // d_in[7] gat_bias: cancels in training-mode BN — unused
    const float* bn_gamma = (const float*)d_in[8];
    const float* bn_beta  = (const float*)d_in[9];

    int N = in_sizes[0] / DH;
    int E = in_sizes[1] / 2;

    // ---- ws carve (16B aligned) ----
    char* p = (char*)d_ws;
    u16*   xp      = (u16*)p;        p += (size_t)N * DH * 2;   // 25.6 MB
    float* a_src   = (float*)p;      p += (size_t)N * NH * 4;   //  1.6 MB
    float* a_dst   = (float*)p;      p += (size_t)N * NH * 4;   //  1.6 MB
    char* zero_begin = p;
    float* denom   = (float*)p;      p += (size_t)N * NH * 4;   //  1.6 MB
    float* colsum  = (float*)p;      p += DH * 4;
    float* colsumsq= (float*)p;      p += DH * 4;
    size_t zero_bytes = (size_t)(p - zero_begin);
    float* agg     = (float*)p;      // N*CB fp32
    size_t base_bytes = (size_t)(p - (char*)d_ws);

    int CB = 128;
    while (CB > 8 && base_bytes + (size_t)N * CB * 4 > ws_size) CB >>= 1;
    int lgCB = 31 - __builtin_clz((unsigned)CB);
    int passes = DH / CB;

    hipMemsetAsync(zero_begin, 0, zero_bytes, stream);

    gemm_naive<<<(N * 256 + 255) / 256, 256, 0, stream>>>(
        x, lin_w, lin_b, gat_w, (float*)d_out, xp, N);

    att_kernel<<<(N * NH + 255) / 256, 256, 0, stream>>>(xp, att_src, att_dst,
                                                         a_src, a_dst, N);

    int tot = E + N;
    ek_sum<<<(tot + 255) / 256, 256, 0, stream>>>(ei, E, N, a_src, a_dst, denom);

    long long aggThreads = (long long)tot * 32;
    unsigned int aggBlocks = (unsigned int)((aggThreads + 255) / 256);

    for (int pass = 0; pass < passes; pass++) {
        hipMemsetAsync(agg, 0, (size_t)N * CB * 4, stream);
        ek_agg<<<aggBlocks, 256, 0, stream>>>(ei, E, N, a_src, a_dst,
                                              denom, xp, agg, pass, CB);
        stats_kernel<<<512, 256, 0, stream>>>(agg, N, CB, lgCB, pass,
                                              colsum, colsumsq);
        final_kernel<<<((N * CB) + 255) / 256, 256, 0, stream>>>(
            agg, colsum, colsumsq, bn_gamma, bn_beta, (float*)d_out,
            N, CB, lgCB, pass);
    }
}

// Round 5
// 1247.607 us; speedup vs baseline: 1.5457x; 1.5457x over previous
//
#include <hip/hip_runtime.h>
#include <stdint.h>

typedef unsigned short u16;
typedef __attribute__((ext_vector_type(8))) short short8;
typedef __attribute__((ext_vector_type(4))) float floatx4;

#define DH 128   // D = H*C
#define NH 4     // heads
#define CH 32    // channels per head

__device__ __forceinline__ float bf2f(u16 u) {
    union { unsigned int i; float f; } c; c.i = ((unsigned int)u) << 16; return c.f;
}
__device__ __forceinline__ u16 f2bf(float f) {
    union { float f; unsigned int i; } c; c.f = f;
    unsigned int x = c.i;
    x += 0x7FFFu + ((x >> 16) & 1u);   // round-to-nearest-even
    return (u16)(x >> 16);
}
__device__ __forceinline__ float lrelu(float v) { return v > 0.f ? v : 0.2f * v; }

// ---- repack [lin_w | gat_w] (f32) into MFMA B-fragment order (bf16) ------
// wpack[((ct*4+ks)*64 + lane)*8 + j] = W[ks*32 + (lane>>4)*8 + j][ct*16 + (lane&15)]
__global__ void repack_w(const float* __restrict__ lin_w, const float* __restrict__ gat_w,
                         u16* __restrict__ wpack) {
    int t = blockIdx.x * blockDim.x + threadIdx.x;   // 0 .. 32767
    int j    = t & 7;
    int lane = (t >> 3) & 63;
    int ks   = (t >> 9) & 3;
    int ct   = t >> 11;
    int k    = ks * 32 + (lane >> 4) * 8 + j;
    int col  = ct * 16 + (lane & 15);
    float v = (col < DH) ? lin_w[k * DH + col] : gat_w[k * DH + (col - DH)];
    wpack[t] = f2bf(v);
}

// ---- MFMA GEMM: [N,128] x [128,256] -> h_in (cols 0..127, +lin_b, f32 d_out)
//                                         xp  (cols 128..255, bf16 ws)
__global__ __launch_bounds__(256) void gemm_mfma(
        const float* __restrict__ x, const float* __restrict__ lin_b,
        const u16* __restrict__ wpack, float* __restrict__ h_out,
        u16* __restrict__ xp, int N) {
    int wave = threadIdx.x >> 6;
    int lane = threadIdx.x & 63;
    int rowBase = blockIdx.x * 64 + wave * 16;
    if (rowBase >= N) return;               // N % 16 == 0, so whole wave valid
    int m = lane & 15, quad = lane >> 4;

    // A fragments: A[m=lane&15][k = ks*32 + quad*8 + j]  (convert f32->bf16)
    short8 afr[4];
    const float* xrow = x + (size_t)(rowBase + m) * DH + quad * 8;
    #pragma unroll
    for (int ks = 0; ks < 4; ks++) {
        float4 f0 = *(const float4*)(xrow + ks * 32);
        float4 f1 = *(const float4*)(xrow + ks * 32 + 4);
        short8 a;
        a[0] = (short)f2bf(f0.x); a[1] = (short)f2bf(f0.y);
        a[2] = (short)f2bf(f0.z); a[3] = (short)f2bf(f0.w);
        a[4] = (short)f2bf(f1.x); a[5] = (short)f2bf(f1.y);
        a[6] = (short)f2bf(f1.z); a[7] = (short)f2bf(f1.w);
        afr[ks] = a;
    }

    #pragma unroll 4
    for (int ct = 0; ct < 16; ct++) {
        floatx4 acc = {0.f, 0.f, 0.f, 0.f};
        const short8* bp = (const short8*)wpack + (ct * 4) * 64 + lane;
        #pragma unroll
        for (int ks = 0; ks < 4; ks++) {
            short8 bfr = bp[ks * 64];
            acc = __builtin_amdgcn_mfma_f32_16x16x32_bf16(afr[ks], bfr, acc, 0, 0, 0);
        }
        int col = ct * 16 + m;   // D layout: col=lane&15, row = quad*4 + r
        if (col < DH) {
            float bias = lin_b[col];
            #pragma unroll
            for (int r = 0; r < 4; r++) {
                int row = rowBase + quad * 4 + r;
                h_out[(size_t)row * DH + col] = acc[r] + bias;
            }
        } else {
            int c2 = col - DH;
            #pragma unroll
            for (int r = 0; r < 4; r++) {
                int row = rowBase + quad * 4 + r;
                xp[(size_t)row * DH + c2] = f2bf(acc[r]);
            }
        }
    }
}

// ---- per-(node,head) attention logits ------------------------------------
__global__ __launch_bounds__(256) void att_kernel(
        const u16* __restrict__ xp, const float* __restrict__ att_src,
        const float* __restrict__ att_dst, float* __restrict__ a_src,
        float* __restrict__ a_dst, int N) {
    int t = blockIdx.x * blockDim.x + threadIdx.x;   // t = n*4 + h
    if (t >= N * NH) return;
    int h = t & 3;
    const u16* v    = xp + (size_t)t * CH;
    const float* ws = att_src + h * CH;
    const float* wd = att_dst + h * CH;
    float s = 0.f, d = 0.f;
    for (int c = 0; c < CH; c++) {
        float xv = bf2f(v[c]);
        s += xv * ws[c];
        d += xv * wd[c];
    }
    a_src[t] = s;
    a_dst[t] = d;
}

// ---- denom[d][h] += exp(e)  (no max subtraction: |e| <~ 3, exp safe) ----
__global__ __launch_bounds__(256) void ek_sum(
        const int* __restrict__ ei, int E, int N,
        const float* __restrict__ a_src, const float* __restrict__ a_dst,
        float* __restrict__ denom) {
    int i = blockIdx.x * blockDim.x + threadIdx.x;
    if (i >= E + N) return;
    int s, d;
    if (i < E) { s = ei[i]; d = ei[E + i]; } else { s = i - E; d = s; }
    s = min(max(s, 0), N - 1);
    d = min(max(d, 0), N - 1);
    for (int h = 0; h < NH; h++) {
        float e = lrelu(a_src[s * NH + h] + a_dst[d * NH + h]);
        atomicAdd(&denom[d * NH + h], expf(e));
    }
}

// ---- agg[d][c] += alpha * xp[s][c] for c in this pass's chunk -----------
__global__ __launch_bounds__(256) void ek_agg(
        const int* __restrict__ ei, int E, int N,
        const float* __restrict__ a_src, const float* __restrict__ a_dst,
        const float* __restrict__ denom, const u16* __restrict__ xp,
        float* __restrict__ agg, int pass, int CB) {
    long long t = (long long)blockIdx.x * blockDim.x + threadIdx.x;
    int i = (int)(t >> 5);
    int l = (int)(t & 31);
    if (i >= E + N) return;
    int s, d;
    if (i < E) { s = ei[i]; d = ei[E + i]; } else { s = i - E; d = s; }
    s = min(max(s, 0), N - 1);
    d = min(max(d, 0), N - 1);
    float al[NH];
    for (int h = 0; h < NH; h++) {
        float e = lrelu(a_src[s * NH + h] + a_dst[d * NH + h]);
        al[h] = expf(e) / denom[d * NH + h];
    }
    const u16* xr = xp + (size_t)s * DH;
    float* ar = agg + (size_t)d * CB;
    for (int c = l; c < CB; c += 32) {
        int gcol = pass * CB + c;
        atomicAdd(ar + c, al[gcol >> 5] * bf2f(xr[gcol]));
    }
}

// ---- BN column stats for one pass chunk ---------------------------------
__global__ __launch_bounds__(256) void stats_kernel(
        const float* __restrict__ agg, int N, int CB, int lgCB, int pass,
        float* __restrict__ colsum, float* __restrict__ colsumsq) {
    int c_local = threadIdx.x & (CB - 1);
    int sub     = threadIdx.x >> lgCB;
    int stride  = 256 >> lgCB;
    int rpb = (N + gridDim.x - 1) / gridDim.x;
    int r0  = blockIdx.x * rpb;
    int r1  = min(N, r0 + rpb);
    float s1 = 0.f, s2 = 0.f;
    for (int r = r0 + sub; r < r1; r += stride) {
        float v = agg[(size_t)r * CB + c_local];
        s1 += v; s2 += v * v;
    }
    atomicAdd(&colsum[pass * CB + c_local], s1);
    atomicAdd(&colsumsq[pass * CB + c_local], s2);
}

// ---- BN normalize + ELU + residual --------------------------------------
// gat_bias cancels exactly in training-mode BN (shifts column mean only)
__global__ __launch_bounds__(256) void final_kernel(
        const float* __restrict__ agg, const float* __restrict__ colsum,
        const float* __restrict__ colsumsq, const float* __restrict__ gamma,
        const float* __restrict__ beta, float* __restrict__ out, int N,
        int CB, int lgCB, int pass) {
    int idx = blockIdx.x * blockDim.x + threadIdx.x;
    if (idx >= N * CB) return;
    int c_local = idx & (CB - 1);
    int row     = idx >> lgCB;
    int gcol    = pass * CB + c_local;
    float inv_n = 1.0f / (float)N;
    float mu  = colsum[gcol] * inv_n;
    float var = colsumsq[gcol] * inv_n - mu * mu;
    float rstd = rsqrtf(var + 1e-5f);
    float v = (agg[idx] - mu) * rstd * gamma[gcol] + beta[gcol];
    v = v > 0.f ? v : (expf(v) - 1.f);            // ELU(alpha=1)
    size_t o = (size_t)row * DH + gcol;
    float r = out[o] + v;                         // + h_in (already in d_out)
    // tripwire: non-finite -> 512 sentinel (diagnostic, no-op when correct)
    if (!(r >= -1e30f && r <= 1e30f)) r = 512.0f;
    out[o] = r;
}

extern "C" void kernel_launch(void* const* d_in, const int* in_sizes, int n_in,
                              void* d_out, int out_size, void* d_ws, size_t ws_size,
                              hipStream_t stream) {
    const float* x        = (const float*)d_in[0];
    const int*   ei       = (const int*)d_in[1];
    const float* lin_w    = (const float*)d_in[2];
    const float* lin_b    = (const float*)d_in[3];
    const float* gat_w    = (const float*)d_in[4];
    const float* att_src  = (const float*)d_in[5];
    const float* att_dst  = (const float*)d_in[6];
    // d_in[7] gat_bias: cancels in training-mode BN — unused
    const float* bn_gamma = (const float*)d_in[8];
    const float* bn_beta  = (const float*)d_in[9];

    int N = in_sizes[0] / DH;
    int E = in_sizes[1] / 2;

    // ---- ws carve (16B aligned) ----
    char* p = (char*)d_ws;
    u16*   xp      = (u16*)p;        p += (size_t)N * DH * 2;   // 25.6 MB
    float* a_src   = (float*)p;      p += (size_t)N * NH * 4;   //  1.6 MB
    float* a_dst   = (float*)p;      p += (size_t)N * NH * 4;   //  1.6 MB
    u16*   wpack   = (u16*)p;        p += 32768 * 2;            // 64 KB
    char* zero_begin = p;
    float* denom   = (float*)p;      p += (size_t)N * NH * 4;   //  1.6 MB
    float* colsum  = (float*)p;      p += DH * 4;
    float* colsumsq= (float*)p;      p += DH * 4;
    size_t zero_bytes = (size_t)(p - zero_begin);
    float* agg     = (float*)p;      // N*CB fp32
    size_t base_bytes = (size_t)(p - (char*)d_ws);

    int CB = 128;
    while (CB > 8 && base_bytes + (size_t)N * CB * 4 > ws_size) CB >>= 1;
    int lgCB = 31 - __builtin_clz((unsigned)CB);
    int passes = DH / CB;

    hipMemsetAsync(zero_begin, 0, zero_bytes, stream);

    repack_w<<<(16 * 4 * 64 * 8) / 256, 256, 0, stream>>>(lin_w, gat_w, wpack);

    gemm_mfma<<<(N + 63) / 64, 256, 0, stream>>>(x, lin_b, wpack,
                                                 (float*)d_out, xp, N);

    att_kernel<<<(N * NH + 255) / 256, 256, 0, stream>>>(xp, att_src, att_dst,
                                                         a_src, a_dst, N);

    int tot = E + N;
    ek_sum<<<(tot + 255) / 256, 256, 0, stream>>>(ei, E, N, a_src, a_dst, denom);

    long long aggThreads = (long long)tot * 32;
    unsigned int aggBlocks = (unsigned int)((aggThreads + 255) / 256);

    for (int pass = 0; pass < passes; pass++) {
        hipMemsetAsync(agg, 0, (size_t)N * CB * 4, stream);
        ek_agg<<<aggBlocks, 256, 0, stream>>>(ei, E, N, a_src, a_dst,
                                              denom, xp, agg, pass, CB);
        stats_kernel<<<512, 256, 0, stream>>>(agg, N, CB, lgCB, pass,
                                              colsum, colsumsq);
        final_kernel<<<((N * CB) + 255) / 256, 256, 0, stream>>>(
            agg, colsum, colsumsq, bn_gamma, bn_beta, (float*)d_out,
            N, CB, lgCB, pass);
    }
}

// Round 6
// 941.801 us; speedup vs baseline: 2.0477x; 1.3247x over previous
//
#include <hip/hip_runtime.h>
#include <stdint.h>

typedef unsigned short u16;
typedef __attribute__((ext_vector_type(8))) short short8;
typedef __attribute__((ext_vector_type(4))) float floatx4;

#define DH 128   // D = H*C
#define NH 4     // heads
#define CH 32    // channels per head

__device__ __forceinline__ float bf2f(u16 u) {
    union { unsigned int i; float f; } c; c.i = ((unsigned int)u) << 16; return c.f;
}
__device__ __forceinline__ u16 f2bf(float f) {
    union { float f; unsigned int i; } c; c.f = f;
    unsigned int x = c.i;
    x += 0x7FFFu + ((x >> 16) & 1u);   // round-to-nearest-even
    return (u16)(x >> 16);
}
__device__ __forceinline__ float lrelu(float v) { return v > 0.f ? v : 0.2f * v; }

// ---- repack [lin_w | gat_w] (f32) into MFMA B-fragment order (bf16) ------
__global__ void repack_w(const float* __restrict__ lin_w, const float* __restrict__ gat_w,
                         u16* __restrict__ wpack) {
    int t = blockIdx.x * blockDim.x + threadIdx.x;   // 0 .. 32767
    int j    = t & 7;
    int lane = (t >> 3) & 63;
    int ks   = (t >> 9) & 3;
    int ct   = t >> 11;
    int k    = ks * 32 + (lane >> 4) * 8 + j;
    int col  = ct * 16 + (lane & 15);
    float v = (col < DH) ? lin_w[k * DH + col] : gat_w[k * DH + (col - DH)];
    wpack[t] = f2bf(v);
}

// ---- MFMA GEMM: [N,128] x [128,256] -> h_in (f32 d_out) ; xp (bf16 ws) ---
__global__ __launch_bounds__(256) void gemm_mfma(
        const float* __restrict__ x, const float* __restrict__ lin_b,
        const u16* __restrict__ wpack, float* __restrict__ h_out,
        u16* __restrict__ xp, int N) {
    int wave = threadIdx.x >> 6;
    int lane = threadIdx.x & 63;
    int rowBase = blockIdx.x * 64 + wave * 16;
    if (rowBase >= N) return;
    int m = lane & 15, quad = lane >> 4;

    short8 afr[4];
    const float* xrow = x + (size_t)(rowBase + m) * DH + quad * 8;
    #pragma unroll
    for (int ks = 0; ks < 4; ks++) {
        float4 f0 = *(const float4*)(xrow + ks * 32);
        float4 f1 = *(const float4*)(xrow + ks * 32 + 4);
        short8 a;
        a[0] = (short)f2bf(f0.x); a[1] = (short)f2bf(f0.y);
        a[2] = (short)f2bf(f0.z); a[3] = (short)f2bf(f0.w);
        a[4] = (short)f2bf(f1.x); a[5] = (short)f2bf(f1.y);
        a[6] = (short)f2bf(f1.z); a[7] = (short)f2bf(f1.w);
        afr[ks] = a;
    }

    #pragma unroll 4
    for (int ct = 0; ct < 16; ct++) {
        floatx4 acc = {0.f, 0.f, 0.f, 0.f};
        const short8* bp = (const short8*)wpack + (ct * 4) * 64 + lane;
        #pragma unroll
        for (int ks = 0; ks < 4; ks++) {
            short8 bfr = bp[ks * 64];
            acc = __builtin_amdgcn_mfma_f32_16x16x32_bf16(afr[ks], bfr, acc, 0, 0, 0);
        }
        int col = ct * 16 + m;   // D: col=lane&15, row=quad*4+r
        if (col < DH) {
            float bias = lin_b[col];
            #pragma unroll
            for (int r = 0; r < 4; r++)
                h_out[(size_t)(rowBase + quad * 4 + r) * DH + col] = acc[r] + bias;
        } else {
            int c2 = col - DH;
            #pragma unroll
            for (int r = 0; r < 4; r++)
                xp[(size_t)(rowBase + quad * 4 + r) * DH + c2] = f2bf(acc[r]);
        }
    }
}

// ---- per-(node,head) attention logits ------------------------------------
__global__ __launch_bounds__(256) void att_kernel(
        const u16* __restrict__ xp, const float* __restrict__ att_src,
        const float* __restrict__ att_dst, float* __restrict__ a_src,
        float* __restrict__ a_dst, int N) {
    int t = blockIdx.x * blockDim.x + threadIdx.x;
    if (t >= N * NH) return;
    int h = t & 3;
    const u16* v    = xp + (size_t)t * CH;
    const float* ws = att_src + h * CH;
    const float* wd = att_dst + h * CH;
    float s = 0.f, d = 0.f;
    for (int c = 0; c < CH; c++) {
        float xv = bf2f(v[c]);
        s += xv * ws[c];
        d += xv * wd[c];
    }
    a_src[t] = s;
    a_dst[t] = d;
}

// ---- CSR build: degree histogram (real edges only; self-loops inline) ----
__global__ __launch_bounds__(256) void hist_kernel(
        const int* __restrict__ ei, int E, int N, int* __restrict__ deg) {
    int i = blockIdx.x * blockDim.x + threadIdx.x;
    if (i >= E) return;
    int d = min(max(ei[E + i], 0), N - 1);
    atomicAdd(&deg[d], 1);
}

// ---- scan A: per-block inclusive scan of deg, emit block totals ----------
__global__ __launch_bounds__(256) void scanA(
        const int* __restrict__ deg, int N, int* __restrict__ incl,
        int* __restrict__ blockSums) {
    __shared__ int buf[256];
    int t = threadIdx.x;
    int i = blockIdx.x * 256 + t;
    int v = (i < N) ? deg[i] : 0;
    buf[t] = v;
    __syncthreads();
    for (int s = 1; s < 256; s <<= 1) {
        int add = (t >= s) ? buf[t - s] : 0;
        __syncthreads();
        buf[t] += add;
        __syncthreads();
    }
    if (i < N) incl[i] = buf[t];
    if (t == 255) blockSums[blockIdx.x] = buf[255];
}

// ---- scan B: exclusive scan of block totals (1 block, <=512 entries) -----
__global__ __launch_bounds__(512) void scanB(
        const int* __restrict__ blockSums, int NB, int* __restrict__ blockBase) {
    __shared__ int buf[512];
    int t = threadIdx.x;
    int v = (t < NB) ? blockSums[t] : 0;
    buf[t] = v;
    __syncthreads();
    for (int s = 1; s < 512; s <<= 1) {
        int add = (t >= s) ? buf[t - s] : 0;
        __syncthreads();
        buf[t] += add;
        __syncthreads();
    }
    if (t < NB) blockBase[t] = buf[t] - v;   // exclusive
}

// ---- scan C: offsets = exclusive start; init write cursor ----------------
__global__ __launch_bounds__(256) void scanC(
        const int* __restrict__ deg, const int* __restrict__ incl,
        const int* __restrict__ blockBase, int N,
        int* __restrict__ offsets, int* __restrict__ cursor) {
    int i = blockIdx.x * blockDim.x + threadIdx.x;
    if (i >= N) return;
    int start = blockBase[i >> 8] + incl[i] - deg[i];
    offsets[i] = start;
    cursor[i]  = start;
}

// ---- scatter src-ids into dst-sorted order -------------------------------
__global__ __launch_bounds__(256) void scatter_kernel(
        const int* __restrict__ ei, int E, int N,
        int* __restrict__ cursor, int* __restrict__ col) {
    int i = blockIdx.x * blockDim.x + threadIdx.x;
    if (i >= E) return;
    int s = min(max(ei[i], 0), N - 1);
    int d = min(max(ei[E + i], 0), N - 1);
    int pos = atomicAdd(&cursor[d], 1);
    col[pos] = s;
}

// ---- denom[d][h] += exp(e)  (|e| small; exp safe without max-shift) ------
__global__ __launch_bounds__(256) void ek_sum(
        const int* __restrict__ ei, int E, int N,
        const float* __restrict__ a_src, const float* __restrict__ a_dst,
        float* __restrict__ denom) {
    int i = blockIdx.x * blockDim.x + threadIdx.x;
    if (i >= E + N) return;
    int s, d;
    if (i < E) { s = ei[i]; d = ei[E + i]; } else { s = i - E; d = s; }
    s = min(max(s, 0), N - 1);
    d = min(max(d, 0), N - 1);
    for (int h = 0; h < NH; h++) {
        float e = lrelu(a_src[s * NH + h] + a_dst[d * NH + h]);
        atomicAdd(&denom[d * NH + h], expf(e));
    }
}

// ---- CSR gather: one wave per dst node; register accumulate; 1 write ----
__global__ __launch_bounds__(256) void csr_gather(
        const int* __restrict__ offsets, const int* __restrict__ deg,
        const int* __restrict__ col, const float* __restrict__ a_src,
        const float* __restrict__ a_dst, const float* __restrict__ denom,
        const u16* __restrict__ xp, float* __restrict__ agg,
        int N, int pass, int CB) {
    int node = blockIdx.x * 4 + (threadIdx.x >> 6);
    if (node >= N) return;
    int lane = threadIdx.x & 63;
    int c0 = lane, c1 = lane + 64;
    bool v0 = c0 < CB, v1 = c1 < CB;
    int g0 = min(pass * CB + c0, DH - 1);
    int g1 = v1 ? (pass * CB + c1) : g0;
    int h0 = g0 >> 5, h1 = g1 >> 5;

    float ad0  = a_dst[node * NH + h0], ad1 = a_dst[node * NH + h1];
    float inv0 = 1.f / denom[node * NH + h0];
    float inv1 = 1.f / denom[node * NH + h1];

    // self-loop (s == node)
    const u16* xr = xp + (size_t)node * DH;
    float acc0 = expf(lrelu(a_src[node * NH + h0] + ad0)) * inv0 * bf2f(xr[g0]);
    float acc1 = expf(lrelu(a_src[node * NH + h1] + ad1)) * inv1 * bf2f(xr[g1]);

    int off = offsets[node], dg = deg[node];
    for (int k = 0; k < dg; k++) {
        int s = col[off + k];
        const u16* xs = xp + (size_t)s * DH;
        float b0 = a_src[s * NH + h0], b1 = a_src[s * NH + h1];
        acc0 += expf(lrelu(b0 + ad0)) * inv0 * bf2f(xs[g0]);
        acc1 += expf(lrelu(b1 + ad1)) * inv1 * bf2f(xs[g1]);
    }
    float* ar = agg + (size_t)node * CB;
    if (v0) ar[c0] = acc0;
    if (v1) ar[c1] = acc1;
}

// ---- BN column stats for one pass chunk ---------------------------------
__global__ __launch_bounds__(256) void stats_kernel(
        const float* __restrict__ agg, int N, int CB, int lgCB, int pass,
        float* __restrict__ colsum, float* __restrict__ colsumsq) {
    int c_local = threadIdx.x & (CB - 1);
    int sub     = threadIdx.x >> lgCB;
    int stride  = 256 >> lgCB;
    int rpb = (N + gridDim.x - 1) / gridDim.x;
    int r0  = blockIdx.x * rpb;
    int r1  = min(N, r0 + rpb);
    float s1 = 0.f, s2 = 0.f;
    for (int r = r0 + sub; r < r1; r += stride) {
        float v = agg[(size_t)r * CB + c_local];
        s1 += v; s2 += v * v;
    }
    atomicAdd(&colsum[pass * CB + c_local], s1);
    atomicAdd(&colsumsq[pass * CB + c_local], s2);
}

// ---- BN normalize + ELU + residual --------------------------------------
// gat_bias cancels exactly in training-mode BN (shifts column mean only)
__global__ __launch_bounds__(256) void final_kernel(
        const float* __restrict__ agg, const float* __restrict__ colsum,
        const float* __restrict__ colsumsq, const float* __restrict__ gamma,
        const float* __restrict__ beta, float* __restrict__ out, int N,
        int CB, int lgCB, int pass) {
    int idx = blockIdx.x * blockDim.x + threadIdx.x;
    if (idx >= N * CB) return;
    int c_local = idx & (CB - 1);
    int row     = idx >> lgCB;
    int gcol    = pass * CB + c_local;
    float inv_n = 1.0f / (float)N;
    float mu  = colsum[gcol] * inv_n;
    float var = colsumsq[gcol] * inv_n - mu * mu;
    float rstd = rsqrtf(var + 1e-5f);
    float v = (agg[idx] - mu) * rstd * gamma[gcol] + beta[gcol];
    v = v > 0.f ? v : (expf(v) - 1.f);            // ELU(alpha=1)
    size_t o = (size_t)row * DH + gcol;
    float r = out[o] + v;                         // + h_in (already in d_out)
    if (!(r >= -1e30f && r <= 1e30f)) r = 512.0f; // tripwire sentinel
    out[o] = r;
}

extern "C" void kernel_launch(void* const* d_in, const int* in_sizes, int n_in,
                              void* d_out, int out_size, void* d_ws, size_t ws_size,
                              hipStream_t stream) {
    const float* x        = (const float*)d_in[0];
    const int*   ei       = (const int*)d_in[1];
    const float* lin_w    = (const float*)d_in[2];
    const float* lin_b    = (const float*)d_in[3];
    const float* gat_w    = (const float*)d_in[4];
    const float* att_src  = (const float*)d_in[5];
    const float* att_dst  = (const float*)d_in[6];
    // d_in[7] gat_bias: cancels in training-mode BN — unused
    const float* bn_gamma = (const float*)d_in[8];
    const float* bn_beta  = (const float*)d_in[9];

    int N = in_sizes[0] / DH;
    int E = in_sizes[1] / 2;
    int NB = (N + 255) / 256;   // <= 512 for N <= 131072

    // ---- ws carve (16B aligned) ----
    char* p = (char*)d_ws;
    u16*   xp      = (u16*)p;        p += (size_t)N * DH * 2;   // 25.6 MB
    float* a_src   = (float*)p;      p += (size_t)N * NH * 4;
    float* a_dst   = (float*)p;      p += (size_t)N * NH * 4;
    u16*   wpack   = (u16*)p;        p += 32768 * 2;
    int*   col     = (int*)p;        p += (size_t)E * 4;        //  6.4 MB
    int*   offsets = (int*)p;        p += (size_t)N * 4;
    int*   cursor  = (int*)p;        p += (size_t)N * 4;
    int*   incl    = (int*)p;        p += (size_t)N * 4;
    int*   blockSums = (int*)p;      p += 512 * 4;
    int*   blockBase = (int*)p;      p += 512 * 4;
    char* zero_begin = p;
    int*   deg     = (int*)p;        p += (size_t)N * 4;
    float* denom   = (float*)p;      p += (size_t)N * NH * 4;
    float* colsum  = (float*)p;      p += DH * 4;
    float* colsumsq= (float*)p;      p += DH * 4;
    size_t zero_bytes = (size_t)(p - zero_begin);
    float* agg     = (float*)p;      // N*CB fp32
    size_t base_bytes = (size_t)(p - (char*)d_ws);

    int CB = 128;
    while (CB > 8 && base_bytes + (size_t)N * CB * 4 > ws_size) CB >>= 1;
    int lgCB = 31 - __builtin_clz((unsigned)CB);
    int passes = DH / CB;

    hipMemsetAsync(zero_begin, 0, zero_bytes, stream);

    repack_w<<<(16 * 4 * 64 * 8) / 256, 256, 0, stream>>>(lin_w, gat_w, wpack);

    gemm_mfma<<<(N + 63) / 64, 256, 0, stream>>>(x, lin_b, wpack,
                                                 (float*)d_out, xp, N);

    att_kernel<<<(N * NH + 255) / 256, 256, 0, stream>>>(xp, att_src, att_dst,
                                                         a_src, a_dst, N);

    // CSR build
    hist_kernel<<<(E + 255) / 256, 256, 0, stream>>>(ei, E, N, deg);
    scanA<<<NB, 256, 0, stream>>>(deg, N, incl, blockSums);
    scanB<<<1, 512, 0, stream>>>(blockSums, NB, blockBase);
    scanC<<<NB, 256, 0, stream>>>(deg, incl, blockBase, N, offsets, cursor);
    scatter_kernel<<<(E + 255) / 256, 256, 0, stream>>>(ei, E, N, cursor, col);

    int tot = E + N;
    ek_sum<<<(tot + 255) / 256, 256, 0, stream>>>(ei, E, N, a_src, a_dst, denom);

    for (int pass = 0; pass < passes; pass++) {
        csr_gather<<<(N + 3) / 4, 256, 0, stream>>>(offsets, deg, col, a_src,
                                                    a_dst, denom, xp, agg,
                                                    N, pass, CB);
        stats_kernel<<<512, 256, 0, stream>>>(agg, N, CB, lgCB, pass,
                                              colsum, colsumsq);
        final_kernel<<<((N * CB) + 255) / 256, 256, 0, stream>>>(
            agg, colsum, colsumsq, bn_gamma, bn_beta, (float*)d_out,
            N, CB, lgCB, pass);
    }
}

// Round 7
// 606.988 us; speedup vs baseline: 3.1771x; 1.5516x over previous
//
#include <hip/hip_runtime.h>
#include <stdint.h>

typedef unsigned short u16;
typedef __attribute__((ext_vector_type(8))) short short8;
typedef __attribute__((ext_vector_type(4))) float floatx4;

#define DH 128   // D = H*C
#define NH 4     // heads
#define CH 32    // channels per head

__device__ __forceinline__ float bf2f(u16 u) {
    union { unsigned int i; float f; } c; c.i = ((unsigned int)u) << 16; return c.f;
}
__device__ __forceinline__ u16 f2bf(float f) {
    union { float f; unsigned int i; } c; c.f = f;
    unsigned int x = c.i;
    x += 0x7FFFu + ((x >> 16) & 1u);   // round-to-nearest-even
    return (u16)(x >> 16);
}
__device__ __forceinline__ float lrelu(float v) { return v > 0.f ? v : 0.2f * v; }

// ---- repack [lin_w | gat_w] (f32) into MFMA B-fragment order (bf16) ------
__global__ void repack_w(const float* __restrict__ lin_w, const float* __restrict__ gat_w,
                         u16* __restrict__ wpack) {
    int t = blockIdx.x * blockDim.x + threadIdx.x;   // 0 .. 32767
    int j    = t & 7;
    int lane = (t >> 3) & 63;
    int ks   = (t >> 9) & 3;
    int ct   = t >> 11;
    int k    = ks * 32 + (lane >> 4) * 8 + j;
    int col  = ct * 16 + (lane & 15);
    float v = (col < DH) ? lin_w[k * DH + col] : gat_w[k * DH + (col - DH)];
    wpack[t] = f2bf(v);
}

// ---- MFMA GEMM: [N,128] x [128,256] -> h_in (f32 d_out) ; xp (bf16 ws) ---
__global__ __launch_bounds__(256) void gemm_mfma(
        const float* __restrict__ x, const float* __restrict__ lin_b,
        const u16* __restrict__ wpack, float* __restrict__ h_out,
        u16* __restrict__ xp, int N) {
    int wave = threadIdx.x >> 6;
    int lane = threadIdx.x & 63;
    int rowBase = blockIdx.x * 64 + wave * 16;
    if (rowBase >= N) return;
    int m = lane & 15, quad = lane >> 4;

    short8 afr[4];
    const float* xrow = x + (size_t)(rowBase + m) * DH + quad * 8;
    #pragma unroll
    for (int ks = 0; ks < 4; ks++) {
        float4 f0 = *(const float4*)(xrow + ks * 32);
        float4 f1 = *(const float4*)(xrow + ks * 32 + 4);
        short8 a;
        a[0] = (short)f2bf(f0.x); a[1] = (short)f2bf(f0.y);
        a[2] = (short)f2bf(f0.z); a[3] = (short)f2bf(f0.w);
        a[4] = (short)f2bf(f1.x); a[5] = (short)f2bf(f1.y);
        a[6] = (short)f2bf(f1.z); a[7] = (short)f2bf(f1.w);
        afr[ks] = a;
    }

    #pragma unroll 4
    for (int ct = 0; ct < 16; ct++) {
        floatx4 acc = {0.f, 0.f, 0.f, 0.f};
        const short8* bp = (const short8*)wpack + (ct * 4) * 64 + lane;
        #pragma unroll
        for (int ks = 0; ks < 4; ks++) {
            short8 bfr = bp[ks * 64];
            acc = __builtin_amdgcn_mfma_f32_16x16x32_bf16(afr[ks], bfr, acc, 0, 0, 0);
        }
        int col = ct * 16 + m;   // D: col=lane&15, row=quad*4+r
        if (col < DH) {
            float bias = lin_b[col];
            #pragma unroll
            for (int r = 0; r < 4; r++)
                h_out[(size_t)(rowBase + quad * 4 + r) * DH + col] = acc[r] + bias;
        } else {
            int c2 = col - DH;
            #pragma unroll
            for (int r = 0; r < 4; r++)
                xp[(size_t)(rowBase + quad * 4 + r) * DH + c2] = f2bf(acc[r]);
        }
    }
}

// ---- per-(node,head) attention logits ------------------------------------
__global__ __launch_bounds__(256) void att_kernel(
        const u16* __restrict__ xp, const float* __restrict__ att_src,
        const float* __restrict__ att_dst, float* __restrict__ a_src,
        float* __restrict__ a_dst, int N) {
    int t = blockIdx.x * blockDim.x + threadIdx.x;
    if (t >= N * NH) return;
    int h = t & 3;
    const u16* v    = xp + (size_t)t * CH;
    const float* ws = att_src + h * CH;
    const float* wd = att_dst + h * CH;
    float s = 0.f, d = 0.f;
    for (int c = 0; c < CH; c++) {
        float xv = bf2f(v[c]);
        s += xv * ws[c];
        d += xv * wd[c];
    }
    a_src[t] = s;
    a_dst[t] = d;
}

// ---- CSR build: degree histogram (real edges only; self-loops inline) ----
__global__ __launch_bounds__(256) void hist_kernel(
        const int* __restrict__ ei, int E, int N, int* __restrict__ deg) {
    int i = blockIdx.x * blockDim.x + threadIdx.x;
    if (i >= E) return;
    int d = min(max(ei[E + i], 0), N - 1);
    atomicAdd(&deg[d], 1);
}

// ---- scan A: per-block inclusive scan of deg, emit block totals ----------
__global__ __launch_bounds__(256) void scanA(
        const int* __restrict__ deg, int N, int* __restrict__ incl,
        int* __restrict__ blockSums) {
    __shared__ int buf[256];
    int t = threadIdx.x;
    int i = blockIdx.x * 256 + t;
    int v = (i < N) ? deg[i] : 0;
    buf[t] = v;
    __syncthreads();
    for (int s = 1; s < 256; s <<= 1) {
        int add = (t >= s) ? buf[t - s] : 0;
        __syncthreads();
        buf[t] += add;
        __syncthreads();
    }
    if (i < N) incl[i] = buf[t];
    if (t == 255) blockSums[blockIdx.x] = buf[255];
}

// ---- scan B: exclusive scan of block totals (1 block, <=512 entries) -----
__global__ __launch_bounds__(512) void scanB(
        const int* __restrict__ blockSums, int NB, int* __restrict__ blockBase) {
    __shared__ int buf[512];
    int t = threadIdx.x;
    int v = (t < NB) ? blockSums[t] : 0;
    buf[t] = v;
    __syncthreads();
    for (int s = 1; s < 512; s <<= 1) {
        int add = (t >= s) ? buf[t - s] : 0;
        __syncthreads();
        buf[t] += add;
        __syncthreads();
    }
    if (t < NB) blockBase[t] = buf[t] - v;   // exclusive
}

// ---- scan C: offsets = exclusive start; init write cursor ----------------
__global__ __launch_bounds__(256) void scanC(
        const int* __restrict__ deg, const int* __restrict__ incl,
        const int* __restrict__ blockBase, int N,
        int* __restrict__ offsets, int* __restrict__ cursor) {
    int i = blockIdx.x * blockDim.x + threadIdx.x;
    if (i >= N) return;
    int start = blockBase[i >> 8] + incl[i] - deg[i];
    offsets[i] = start;
    cursor[i]  = start;
}

// ---- scatter src-ids into dst-sorted order -------------------------------
__global__ __launch_bounds__(256) void scatter_kernel(
        const int* __restrict__ ei, int E, int N,
        int* __restrict__ cursor, int* __restrict__ col) {
    int i = blockIdx.x * blockDim.x + threadIdx.x;
    if (i >= E) return;
    int s = min(max(ei[i], 0), N - 1);
    int d = min(max(ei[E + i], 0), N - 1);
    int pos = atomicAdd(&cursor[d], 1);
    col[pos] = s;
}

// ---- CSR gather + fused softmax denominator ------------------------------
// one wave per dst node; unnormalized weighted sum + denom in registers;
// single normalized write per output element. No atomics, no ek_sum pass.
__global__ __launch_bounds__(256) void csr_gather(
        const int* __restrict__ offsets, const int* __restrict__ deg,
        const int* __restrict__ col, const float* __restrict__ a_src,
        const float* __restrict__ a_dst, const u16* __restrict__ xp,
        float* __restrict__ agg, int N, int pass, int CB) {
    int node = blockIdx.x * 4 + (threadIdx.x >> 6);
    if (node >= N) return;
    int lane = threadIdx.x & 63;
    int c0 = lane, c1 = lane + 64;
    bool v0 = c0 < CB, v1 = c1 < CB;
    int g0 = min(pass * CB + c0, DH - 1);
    int g1 = v1 ? (pass * CB + c1) : g0;
    int h0 = g0 >> 5, h1 = g1 >> 5;

    float ad0 = a_dst[node * NH + h0], ad1 = a_dst[node * NH + h1];

    // self-loop (s == node)
    const u16* xr = xp + (size_t)node * DH;
    float w0 = expf(lrelu(a_src[node * NH + h0] + ad0));
    float w1 = expf(lrelu(a_src[node * NH + h1] + ad1));
    float acc0 = w0 * bf2f(xr[g0]);
    float acc1 = w1 * bf2f(xr[g1]);
    float den0 = w0, den1 = w1;

    int off = offsets[node], dg = deg[node];
    for (int k = 0; k < dg; k++) {
        int s = col[off + k];
        const u16* xs = xp + (size_t)s * DH;
        float e0 = expf(lrelu(a_src[s * NH + h0] + ad0));
        float e1 = expf(lrelu(a_src[s * NH + h1] + ad1));
        acc0 += e0 * bf2f(xs[g0]);
        acc1 += e1 * bf2f(xs[g1]);
        den0 += e0;
        den1 += e1;
    }
    float* ar = agg + (size_t)node * CB;
    if (v0) ar[c0] = acc0 / den0;
    if (v1) ar[c1] = acc1 / den1;
}

// ---- BN column stats for one pass chunk ---------------------------------
__global__ __launch_bounds__(256) void stats_kernel(
        const float* __restrict__ agg, int N, int CB, int lgCB, int pass,
        float* __restrict__ colsum, float* __restrict__ colsumsq) {
    int c_local = threadIdx.x & (CB - 1);
    int sub     = threadIdx.x >> lgCB;
    int stride  = 256 >> lgCB;
    int rpb = (N + gridDim.x - 1) / gridDim.x;
    int r0  = blockIdx.x * rpb;
    int r1  = min(N, r0 + rpb);
    float s1 = 0.f, s2 = 0.f;
    for (int r = r0 + sub; r < r1; r += stride) {
        float v = agg[(size_t)r * CB + c_local];
        s1 += v; s2 += v * v;
    }
    atomicAdd(&colsum[pass * CB + c_local], s1);
    atomicAdd(&colsumsq[pass * CB + c_local], s2);
}

// ---- BN normalize + ELU + residual --------------------------------------
// gat_bias cancels exactly in training-mode BN (shifts column mean only)
__global__ __launch_bounds__(256) void final_kernel(
        const float* __restrict__ agg, const float* __restrict__ colsum,
        const float* __restrict__ colsumsq, const float* __restrict__ gamma,
        const float* __restrict__ beta, float* __restrict__ out, int N,
        int CB, int lgCB, int pass) {
    int idx = blockIdx.x * blockDim.x + threadIdx.x;
    if (idx >= N * CB) return;
    int c_local = idx & (CB - 1);
    int row     = idx >> lgCB;
    int gcol    = pass * CB + c_local;
    float inv_n = 1.0f / (float)N;
    float mu  = colsum[gcol] * inv_n;
    float var = colsumsq[gcol] * inv_n - mu * mu;
    float rstd = rsqrtf(var + 1e-5f);
    float v = (agg[idx] - mu) * rstd * gamma[gcol] + beta[gcol];
    v = v > 0.f ? v : (expf(v) - 1.f);            // ELU(alpha=1)
    size_t o = (size_t)row * DH + gcol;
    float r = out[o] + v;                         // + h_in (already in d_out)
    if (!(r >= -1e30f && r <= 1e30f)) r = 512.0f; // tripwire sentinel
    out[o] = r;
}

extern "C" void kernel_launch(void* const* d_in, const int* in_sizes, int n_in,
                              void* d_out, int out_size, void* d_ws, size_t ws_size,
                              hipStream_t stream) {
    const float* x        = (const float*)d_in[0];
    const int*   ei       = (const int*)d_in[1];
    const float* lin_w    = (const float*)d_in[2];
    const float* lin_b    = (const float*)d_in[3];
    const float* gat_w    = (const float*)d_in[4];
    const float* att_src  = (const float*)d_in[5];
    const float* att_dst  = (const float*)d_in[6];
    // d_in[7] gat_bias: cancels in training-mode BN — unused
    const float* bn_gamma = (const float*)d_in[8];
    const float* bn_beta  = (const float*)d_in[9];

    int N = in_sizes[0] / DH;
    int E = in_sizes[1] / 2;
    int NB = (N + 255) / 256;   // <= 512 for N <= 131072

    // ---- ws carve (16B aligned) ----
    char* p = (char*)d_ws;
    u16*   xp      = (u16*)p;        p += (size_t)N * DH * 2;   // 25.6 MB
    float* a_src   = (float*)p;      p += (size_t)N * NH * 4;
    float* a_dst   = (float*)p;      p += (size_t)N * NH * 4;
    u16*   wpack   = (u16*)p;        p += 32768 * 2;
    int*   col     = (int*)p;        p += (size_t)E * 4;        //  6.4 MB
    int*   offsets = (int*)p;        p += (size_t)N * 4;
    int*   cursor  = (int*)p;        p += (size_t)N * 4;
    int*   incl    = (int*)p;        p += (size_t)N * 4;
    int*   blockSums = (int*)p;      p += 512 * 4;
    int*   blockBase = (int*)p;      p += 512 * 4;
    char* zero_begin = p;
    int*   deg     = (int*)p;        p += (size_t)N * 4;
    float* colsum  = (float*)p;      p += DH * 4;
    float* colsumsq= (float*)p;      p += DH * 4;
    size_t zero_bytes = (size_t)(p - zero_begin);
    float* agg     = (float*)p;      // N*CB fp32
    size_t base_bytes = (size_t)(p - (char*)d_ws);

    int CB = 128;
    while (CB > 8 && base_bytes + (size_t)N * CB * 4 > ws_size) CB >>= 1;
    int lgCB = 31 - __builtin_clz((unsigned)CB);
    int passes = DH / CB;

    hipMemsetAsync(zero_begin, 0, zero_bytes, stream);

    repack_w<<<(16 * 4 * 64 * 8) / 256, 256, 0, stream>>>(lin_w, gat_w, wpack);

    gemm_mfma<<<(N + 63) / 64, 256, 0, stream>>>(x, lin_b, wpack,
                                                 (float*)d_out, xp, N);

    att_kernel<<<(N * NH + 255) / 256, 256, 0, stream>>>(xp, att_src, att_dst,
                                                         a_src, a_dst, N);

    // CSR build
    hist_kernel<<<(E + 255) / 256, 256, 0, stream>>>(ei, E, N, deg);
    scanA<<<NB, 256, 0, stream>>>(deg, N, incl, blockSums);
    scanB<<<1, 512, 0, stream>>>(blockSums, NB, blockBase);
    scanC<<<NB, 256, 0, stream>>>(deg, incl, blockBase, N, offsets, cursor);
    scatter_kernel<<<(E + 255) / 256, 256, 0, stream>>>(ei, E, N, cursor, col);

    for (int pass = 0; pass < passes; pass++) {
        csr_gather<<<(N + 3) / 4, 256, 0, stream>>>(offsets, deg, col, a_src,
                                                    a_dst, xp, agg, N, pass, CB);
        stats_kernel<<<512, 256, 0, stream>>>(agg, N, CB, lgCB, pass,
                                              colsum, colsumsq);
        final_kernel<<<((N * CB) + 255) / 256, 256, 0, stream>>>(
            agg, colsum, colsumsq, bn_gamma, bn_beta, (float*)d_out,
            N, CB, lgCB, pass);
    }
}